// Round 18
// baseline (141.497 us; speedup 1.0000x reference)
//
#include <hip/hip_runtime.h>
#include <math.h>

// GEBLNet via Gram-matrix reduction.
// R35 = R34's w1-LDS staging + 6-pass slice shrink -> 3 blocks/CU.
// EVIDENCE (R34 decomposition): staging cut per-BLOCK latency 25.7->18.7us
// (-27%, the critical-path theory confirmed) but 47.6KB/block -> 2 blk/CU
// against the ~102KB pool (2.15x47616=102KB, 3rd confirmation) -> net
// regress. This round keeps staging and buys the 3rd block back:
//   - phase 2 in SIX passes of 2 u's: bs[234]=1872B, union w/ gv+scratch
//     (1976B); slice = 1040(We)+1976+864(Hs) = 3880 B/wave.
//   - block total = 16224(w1L) + 4x3880 = 31744 B -> 3 blk/CU (12 waves).
//   - R30's multi-pass penalty is defused: per-pass 2a critical path is
//     now LDS-only (w1L broadcasts, no VMEM latency per pass).
// Projection: T_blk ~19-22us, X=3/T -> dur ~53-59us.
// LEDGER: proven = conflict removal (R18), load-ILP (R19), pk-fma (R24),
// chain split (R25/R26), 4-wave pack (R28), LDS pool ~102KB (R30/R34),
// w1-staging cuts T_blk 27% (R34). Falsified = VMEM count (R21), DS count
// (R23), pt-amortization (R22), TLP as binder (R30), L1-line fan-out (R33).
// LESSON (R6): unions only, no reinterpret-cast of locals.

#define NPTS 8192
#define THRESH 0.001f

typedef float f32x2 __attribute__((ext_vector_type(2)));

// Wave-local "barrier": drain this wave's outstanding LDS ops.
static __device__ __forceinline__ void wsync() {
    asm volatile("s_waitcnt lgkmcnt(0)" ::: "memory");
}

// --- independent halves of complex MAC: acc += cc * ee ---
static __device__ __forceinline__ void cmacA(f32x2& acc, f32x2 cc, f32x2 ee) {
    asm("v_pk_fma_f32 %0, %1, %2, %0 op_sel:[0,0,0] op_sel_hi:[0,1,1]"
        : "+v"(acc) : "v"(cc), "v"(ee));
}
static __device__ __forceinline__ void cmacB(f32x2& acc, f32x2 cc, f32x2 ee) {
    asm("v_pk_fma_f32 %0, %1, %2, %0 op_sel:[1,1,0] op_sel_hi:[1,0,1] neg_lo:[1,0,0]"
        : "+v"(acc) : "v"(cc), "v"(ee));
}
// --- independent halves of conj MAC: acc += A * conj(B) ---
static __device__ __forceinline__ void cmaccA(f32x2& acc, f32x2 A, f32x2 B) {
    asm("v_pk_fma_f32 %0, %1, %2, %0 op_sel:[0,0,0] op_sel_hi:[0,1,1] neg_hi:[1,0,0]"
        : "+v"(acc) : "v"(A), "v"(B));
}
static __device__ __forceinline__ void cmaccB(f32x2& acc, f32x2 A, f32x2 B) {
    asm("v_pk_fma_f32 %0, %1, %2, %0 op_sel:[1,1,0] op_sel_hi:[1,0,1]"
        : "+v"(acc) : "v"(A), "v"(B));
}
// --- independent halves of P5 dot ---
static __device__ __forceinline__ void cdotA(f32x2& acc, f32x2 gv, f32x2 cA) {
    asm("v_pk_fma_f32 %0, %1, %2, %0 op_sel:[0,0,0] op_sel_hi:[0,1,1]"
        : "+v"(acc) : "v"(gv), "v"(cA));
}
static __device__ __forceinline__ void cdotB(f32x2& acc, f32x2 gv, f32x2 cB) {
    asm("v_pk_fma_f32 %0, %1, %2, %0 op_sel:[1,0,0] op_sel_hi:[1,1,1]"
        : "+v"(acc) : "v"(gv), "v"(cB));
}

static __device__ __forceinline__ f32x2 c2(float2 a) {
    f32x2 r; r.x = a.x; r.y = a.y; return r;
}

__global__ void geblnet_setup(const float* __restrict__ w2,
                              float4* __restrict__ CTt) {
    int j = blockIdx.x * blockDim.x + threadIdx.x;
    if (j >= 12 * 169) return;
    int u = j / 169, it = j % 169;
    const float* W = w2 + u * 25 * 25 * 2;
#define WR(v, w) W[((v) * 25 + (w)) * 2]
#define WI(v, w) W[((v) * 25 + (w)) * 2 + 1]
    float c0, c1, c2v, c3;
    if (it < 78) {                       // S pairs, a<=b
        int q = it, a = 0;
        while (q >= 12 - a) { q -= 12 - a; ++a; }
        int b = a + q;
        float ar = WR(a, b) + (a != b ? WR(b, a) : 0.f);
        float ai = WI(a, b) + (a != b ? WI(b, a) : 0.f);
        float br = WR(12 + a, 12 + b) + (a != b ? WR(12 + b, 12 + a) : 0.f);
        float bi = WI(12 + a, 12 + b) + (a != b ? WI(12 + b, 12 + a) : 0.f);
        c0 = ar + br; c1 = bi - ai; c2v = ai + bi; c3 = ar - br;
    } else if (it < 156) {               // Hm pairs, a<=b
        int q = it - 78, a = 0;
        while (q >= 12 - a) { q -= 12 - a; ++a; }
        int b = a + q;
        if (a != b) {
            float gr = WR(a, 12 + b) + WR(12 + b, a);
            float gi = WI(a, 12 + b) + WI(12 + b, a);
            float dr = WR(b, 12 + a) + WR(12 + a, b);
            float di = WI(b, 12 + a) + WI(12 + a, b);
            c0 = gr + dr; c1 = di - gi; c2v = gi + di; c3 = gr - dr;
        } else {
            float er = WR(a, 12 + a) + WR(12 + a, a);
            float ei = WI(a, 12 + a) + WI(12 + a, a);
            c0 = er; c1 = 0.f; c2v = ei; c3 = 0.f;
        }
    } else if (it < 168) {               // trace terms
        int a = it - 156;
        float fr = WR(a, 24) + WR(24, a), fi = WI(a, 24) + WI(24, a);
        float pr = WR(12 + a, 24) + WR(24, 12 + a);
        float pi = WI(12 + a, 24) + WI(24, 12 + a);
        c0 = fr + pr; c1 = pi - fi; c2v = fi + pi; c3 = fr - pr;
    } else {                             // unit-unit
        c0 = 3.f * WR(24, 24); c1 = 0.f; c2v = 3.f * WI(24, 24); c3 = 0.f;
    }
    // Packed layout for P5: pairs (c0,c2) and (c1,c3) adjacent.
    CTt[it * 12 + u] = make_float4(c0, c2v, c1, c3);
#undef WR
#undef WI
}

// Per-wave slice: 3880 B.
//   We[130]: row-major (13 ch, stride 10), live P1-P2.
//   union: bs (live P2 only, 2 u's) / gv+scratch (live P3-P6).
union BsU {
    float2 bs[234];                 // B[uu][v][jk], uu<2, rows 9 (1872 B)
    struct {
        float2 gv[169];             // Gram values, P4->P5   (1352 B)
        float2 tpar[60];            // P5 partials -> P6     (480 B)
        float2 tr1[12];             // traces, P3 -> P4      (96 B)
        float  sc1[12];             // scales, P3 -> P4      (48 B)
    } s;                            // 1976 B
};
struct Slice {
    float2 We[130];                 // 1040 B
    BsU u;                          // 1976 B
    float2 Hs[108];                 //  864 B
};

__global__ __launch_bounds__(256) void geblnet_main(
    const float2* __restrict__ x2,      // (8192, 10, 9) complex
    const float2* __restrict__ w1g,     // (12,13,13) complex
    const float* __restrict__ dw,       // (24,)
    const float* __restrict__ db,       // (1,)
    const float4* __restrict__ CTt,     // (169,12) packed (c0,c2,c1,c3)
    float* __restrict__ out)            // (8192,)
{
    // Block-shared read-only w1 copy (kills per-point w1 VMEM latency).
    __shared__ float2 w1L[2028];        // 16224 B
    __shared__ Slice SL[4];             // 15520 B
    // total 31744 B -> 3 blocks/CU by the ~102KB pool

    const int wid = threadIdx.x >> 6;
    const int t = threadIdx.x & 63;
    const int p = blockIdx.x * 4 + wid;

    Slice* W = &SL[wid];

    // ---- phase 0: stage w1 -> LDS (coalesced), ONE block barrier.
    for (int i = threadIdx.x; i < 2028; i += 256) w1L[i] = w1g[i];
    __syncthreads();                    // w1L read-only hereafter

    // ---- phase 1: ONE coalesced read of x channels 4..9 (54 float2),
    //      write both We layouts (direct ch 0..5, conj-T ch 6..11) + identity.
    if (t < 54) {
        int xc = t / 9, ik = t - xc * 9;
        int i = ik / 3, j = ik - i * 3;
        float2 val = x2[(size_t)p * 90 + 36 + t];       // contiguous 432 B
        W->We[xc * 10 + ik] = val;                       // direct
        W->We[(6 + xc) * 10 + j * 3 + i] = make_float2(val.x, -val.y); // conj-T
    } else if (t < 63) {
        int ik = t - 54;
        W->We[120 + ik] = make_float2((ik % 4 == 0) ? 1.f : 0.f, 0.f); // identity
    }
    wsync();

    // ---- phase 2: layer 1, SIX passes of 2 u's (bs covers 2 u's)
    #pragma unroll 1
    for (int g = 0; g < 6; ++g) {
        const int u0 = g * 2;
        // 2a: B[uu][v][jk] = sum_w w1[u0+uu,v,w] * We[w][jk], uu<2
        //     cc from w1L (conflict-free broadcast), 8 chains.
        {
            int uu = 0, rem = t;
            #pragma unroll 2
            for (int e = t; e < 234; e += 64) {
                int v = rem / 9, jk = rem - v * 9;
                const float2* cp = &w1L[((u0 + uu) * 13 + v) * 13];
                f32x2 a0A = {0.f, 0.f}, a0B = {0.f, 0.f};
                f32x2 a1A = {0.f, 0.f}, a1B = {0.f, 0.f};
                #pragma unroll
                for (int w = 0; w < 12; w += 2) {
                    f32x2 c0 = c2(cp[w]),     e0 = c2(W->We[w * 10 + jk]);
                    f32x2 c1 = c2(cp[w + 1]), e1 = c2(W->We[(w + 1) * 10 + jk]);
                    cmacA(a0A, c0, e0);
                    cmacB(a0B, c0, e0);
                    cmacA(a1A, c1, e1);
                    cmacB(a1B, c1, e1);
                }
                {
                    f32x2 c0 = c2(cp[12]), e0 = c2(W->We[120 + jk]);
                    cmacA(a0A, c0, e0);
                    cmacB(a0B, c0, e0);
                }
                W->u.bs[(uu * 13 + v) * 9 + jk] =
                    make_float2((a0A.x + a0B.x) + (a1A.x + a1B.x),
                                (a0A.y + a0B.y) + (a1A.y + a1B.y));
                rem += 64;
                if (rem >= 117) { rem -= 117; ++uu; }
            }
        }
        wsync();
        // 2b: H[u0+uu][i][k] = sum_{v,j} We[v][i][j] * B[uu][v][j*3+k]
        //     18 lanes active (2 u x 9 ik); 6 chains.
        if (t < 18) {
            int uu = t / 9, ik = t - uu * 9;
            int i = ik / 3, k = ik - i * 3;
            f32x2 h0A = {0.f, 0.f}, h0B = {0.f, 0.f};
            f32x2 h1A = {0.f, 0.f}, h1B = {0.f, 0.f};
            f32x2 h2A = {0.f, 0.f}, h2B = {0.f, 0.f};
            #pragma unroll
            for (int v = 0; v < 13; ++v) {
                const float2* a = &W->We[v * 10 + i * 3];
                const float2* b = &W->u.bs[(uu * 13 + v) * 9 + k];
                f32x2 a0 = c2(a[0]), b0 = c2(b[0]);
                f32x2 a1 = c2(a[1]), b1 = c2(b[3]);
                f32x2 a2 = c2(a[2]), b2 = c2(b[6]);
                cmacA(h0A, a0, b0); cmacB(h0B, a0, b0);
                cmacA(h1A, a1, b1); cmacB(h1B, a1, b1);
                cmacA(h2A, a2, b2); cmacB(h2B, a2, b2);
            }
            W->Hs[(u0 + uu) * 9 + ik] =
                make_float2((h0A.x + h0B.x) + (h1A.x + h1B.x) + (h2A.x + h2B.x),
                            (h0A.y + h0B.y) + (h1A.y + h1B.y) + (h2A.y + h2B.y));
        }
        wsync();
    }

    // ---- phase 3: traces + gerelu + trnorm scales (bs dead; union scratch)
    {
        float2 tt = make_float2(0.f, 0.f);
        float gg = 0.f, tra_v = 0.f;
        if (t < 12) {
            float2 a = W->Hs[t * 9 + 0], b = W->Hs[t * 9 + 4], c = W->Hs[t * 9 + 8];
            tt = make_float2(a.x + b.x + c.x, a.y + b.y + c.y);
            gg = tt.x > 0.f ? tt.x : 0.f;
            tra_v = gg * sqrtf(tt.x * tt.x + tt.y * tt.y);
        }
        float m = tra_v;                 // lanes 12..15 contribute 0
        m += __shfl_xor(m, 1, 16);
        m += __shfl_xor(m, 2, 16);
        m += __shfl_xor(m, 4, 16);
        m += __shfl_xor(m, 8, 16);
        if (t < 12) {
            W->u.s.tr1[t] = tt;
            W->u.s.sc1[t] = gg / fmaxf(m * (1.f / 12.f), THRESH);
        }
    }
    wsync();

    // ---- phase 4: Gram values -> gv (union; bs dead)
    for (int it = t; it < 169; it += 64) {
        float2 val;
        if (it < 156) {
            int q = it < 78 ? it : it - 78;
            float fs = sqrtf(625.0f - 8.0f * (float)q);   // exact at bucket edges
            int a = (int)((25.0f - fs) * 0.5f);
            int b = q - (a * (25 - a)) / 2 + a;
            const float2* Ha = &W->Hs[a * 9];
            const float2* Hb = &W->Hs[b * 9];
            float s = W->u.s.sc1[a] * W->u.s.sc1[b];
            f32x2 v0A = {0.f, 0.f}, v0B = {0.f, 0.f};
            f32x2 v1A = {0.f, 0.f}, v1B = {0.f, 0.f};
            if (it < 78) {                    // S = tr(Aa Ab)
                #pragma unroll
                for (int i = 0; i < 3; ++i)
                    #pragma unroll
                    for (int jj = 0; jj < 3; ++jj) {
                        f32x2 A = c2(Ha[i * 3 + jj]), B = c2(Hb[jj * 3 + i]);
                        if (((i * 3 + jj) & 1) == 0) {
                            cmacA(v0A, A, B); cmacB(v0B, A, B);
                        } else {
                            cmacA(v1A, A, B); cmacB(v1B, A, B);
                        }
                    }
            } else {                          // Hm = tr(Aa Ab^H)
                #pragma unroll
                for (int e = 0; e < 9; ++e) {
                    f32x2 A = c2(Ha[e]), B = c2(Hb[e]);
                    if ((e & 1) == 0) { cmaccA(v0A, A, B); cmaccB(v0B, A, B); }
                    else              { cmaccA(v1A, A, B); cmaccB(v1B, A, B); }
                }
            }
            val = make_float2(s * ((v0A.x + v0B.x) + (v1A.x + v1B.x)),
                              s * ((v0A.y + v0B.y) + (v1A.y + v1B.y)));
        } else if (it < 168) {
            int a = it - 156;
            float s = W->u.s.sc1[a]; float2 tt = W->u.s.tr1[a];
            val = make_float2(s * tt.x, s * tt.y);
        } else {
            val = make_float2(1.f, 0.f);
        }
        W->u.s.gv[it] = val;
    }
    wsync();

    // ---- phase 5: coefficient contraction, lane=(q,u), 60 active
    //      8 chains: 4x unroll x A/B, all NAMED accumulators.
    if (t < 60) {
        int q = t / 12, u = t - q * 12;
        int i0 = q * 34, i1 = (q == 4) ? 169 : i0 + 34;
        f32x2 A0 = {0.f, 0.f}, B0 = {0.f, 0.f};
        f32x2 A1 = {0.f, 0.f}, B1 = {0.f, 0.f};
        f32x2 A2 = {0.f, 0.f}, B2 = {0.f, 0.f};
        f32x2 A3 = {0.f, 0.f}, B3 = {0.f, 0.f};
        int it = i0;
        #pragma unroll 1
        for (; it + 4 <= i1; it += 4) {
            float4 c0v = CTt[(it + 0) * 12 + u];
            float4 c1v = CTt[(it + 1) * 12 + u];
            float4 c2c = CTt[(it + 2) * 12 + u];
            float4 c3v = CTt[(it + 3) * 12 + u];
            f32x2 g0 = c2(W->u.s.gv[it + 0]), g1 = c2(W->u.s.gv[it + 1]);
            f32x2 g2 = c2(W->u.s.gv[it + 2]), g3 = c2(W->u.s.gv[it + 3]);
            f32x2 cA, cB;
            cA.x = c0v.x; cA.y = c0v.y; cB.x = c0v.z; cB.y = c0v.w;
            cdotA(A0, g0, cA); cdotB(B0, g0, cB);
            cA.x = c1v.x; cA.y = c1v.y; cB.x = c1v.z; cB.y = c1v.w;
            cdotA(A1, g1, cA); cdotB(B1, g1, cB);
            cA.x = c2c.x; cA.y = c2c.y; cB.x = c2c.z; cB.y = c2c.w;
            cdotA(A2, g2, cA); cdotB(B2, g2, cB);
            cA.x = c3v.x; cA.y = c3v.y; cB.x = c3v.z; cB.y = c3v.w;
            cdotA(A3, g3, cA); cdotB(B3, g3, cB);
        }
        for (; it < i1; ++it) {
            float4 c = CTt[it * 12 + u];
            f32x2 cA, cB;
            cA.x = c.x; cA.y = c.y; cB.x = c.z; cB.y = c.w;
            f32x2 g = c2(W->u.s.gv[it]);
            cdotA(A0, g, cA); cdotB(B0, g, cB);
        }
        W->u.s.tpar[u * 5 + q] =
            make_float2(((A0.x + B0.x) + (A1.x + B1.x)) +
                        ((A2.x + B2.x) + (A3.x + B3.x)),
                        ((A0.y + B0.y) + (A1.y + B1.y)) +
                        ((A2.y + B2.y) + (A3.y + B3.y)));
    }
    wsync();

    // ---- phase 6: layer-2 gerelu + trnorm + dense head (shuffle reduce)
    {
        float2 tt = make_float2(0.f, 0.f);
        float gg = 0.f, tra_v = 0.f;
        if (t < 12) {
            #pragma unroll
            for (int q = 0; q < 5; ++q) {
                float2 A = W->u.s.tpar[t * 5 + q];
                tt.x += A.x; tt.y += A.y;
            }
            gg = tt.x > 0.f ? tt.x : 0.f;
            tra_v = gg * sqrtf(tt.x * tt.x + tt.y * tt.y);
        }
        float m = tra_v;                 // lanes 12..15 contribute 0
        m += __shfl_xor(m, 1, 16);
        m += __shfl_xor(m, 2, 16);
        m += __shfl_xor(m, 4, 16);
        m += __shfl_xor(m, 8, 16);
        float term = 0.f;
        if (t < 12) {
            float inv = 1.f / fmaxf(m * (1.f / 12.f), THRESH);
            float s = gg * inv * (1.f / 3.f);
            term = s * (tt.x * dw[2 * t] + tt.y * dw[2 * t + 1]);
        }
        term += __shfl_xor(term, 1, 16);
        term += __shfl_xor(term, 2, 16);
        term += __shfl_xor(term, 4, 16);
        term += __shfl_xor(term, 8, 16);
        if (t == 0) out[p] = term + db[0];
    }
}

extern "C" void kernel_launch(void* const* d_in, const int* in_sizes, int n_in,
                              void* d_out, int out_size, void* d_ws, size_t ws_size,
                              hipStream_t stream) {
    const float* x  = (const float*)d_in[0];
    const float* w1 = (const float*)d_in[1];
    const float* w2 = (const float*)d_in[2];
    const float* dw = (const float*)d_in[3];
    const float* db = (const float*)d_in[4];
    float* outp = (float*)d_out;
    float4* CTt = (float4*)d_ws;          // 12*169*16 B = 32448 B

    geblnet_setup<<<(12 * 169 + 255) / 256, 256, 0, stream>>>(w2, CTt);

    geblnet_main<<<NPTS / 4, 256, 0, stream>>>(
        (const float2*)x, (const float2*)w1, dw, db, CTt, outp);
}

// Round 19
// 114.544 us; speedup vs baseline: 1.2353x; 1.2353x over previous
//
#include <hip/hip_runtime.h>
#include <math.h>

// GEBLNet via Gram-matrix reduction.
// R36 = RESTORE R28 (session best: 62.3us kernel / 115.8us bench).
// R35 falsified the last open lever: multi-pass slice shrink costs ~4.6us
// SERIAL per pass (fences + low-lane 2b bursts), overwhelming the 3rd
// resident block. Residency x latency corners now all measured:
//   {2-pass, 3.3blk, no stage} = 62.3 (R28, optimum)
//   {2-pass, 2blk, stage} = 69.7 (R34)   {6-pass, 3blk, stage} = 87.6 (R35)
// DESIGN-SPACE LEDGER (all measured): VMEM count (R21) / pattern (R33),
// DS count (R23), pt-amortization (R22), TLP (R30), VALU issue (R24),
// chain depth (R25/R26 saturated), wg packing (R20/R28), LDS pool ~102KB
// (R30/R34/R35 x4), w1 staging (R34: -27% T_blk, -1.3 blk), pass
// granularity (R30/R35: ~4.6us/pass). R28 maximizes X = N/T.
// Structural floor: ~4700 cy/pt phase-serialized latency, no pipe >45%.
// Wins banked: conflict removal (R18), load-ILP (R19), pk-fma halving
// (R24), A/B chain split (R25/R26), 4-indep-wave packing (R28).

#define NPTS 8192
#define THRESH 0.001f

typedef float f32x2 __attribute__((ext_vector_type(2)));

// Wave-local "barrier": drain this wave's outstanding LDS ops. Sufficient
// for intra-wave producer->consumer through LDS (no inter-wave data here).
static __device__ __forceinline__ void wsync() {
    asm volatile("s_waitcnt lgkmcnt(0)" ::: "memory");
}

// --- independent halves of complex MAC: acc += cc * ee ---
static __device__ __forceinline__ void cmacA(f32x2& acc, f32x2 cc, f32x2 ee) {
    asm("v_pk_fma_f32 %0, %1, %2, %0 op_sel:[0,0,0] op_sel_hi:[0,1,1]"
        : "+v"(acc) : "v"(cc), "v"(ee));
}
static __device__ __forceinline__ void cmacB(f32x2& acc, f32x2 cc, f32x2 ee) {
    asm("v_pk_fma_f32 %0, %1, %2, %0 op_sel:[1,1,0] op_sel_hi:[1,0,1] neg_lo:[1,0,0]"
        : "+v"(acc) : "v"(cc), "v"(ee));
}
// --- independent halves of conj MAC: acc += A * conj(B) ---
static __device__ __forceinline__ void cmaccA(f32x2& acc, f32x2 A, f32x2 B) {
    asm("v_pk_fma_f32 %0, %1, %2, %0 op_sel:[0,0,0] op_sel_hi:[0,1,1] neg_hi:[1,0,0]"
        : "+v"(acc) : "v"(A), "v"(B));
}
static __device__ __forceinline__ void cmaccB(f32x2& acc, f32x2 A, f32x2 B) {
    asm("v_pk_fma_f32 %0, %1, %2, %0 op_sel:[1,1,0] op_sel_hi:[1,0,1]"
        : "+v"(acc) : "v"(A), "v"(B));
}
// --- independent halves of P5 dot ---
static __device__ __forceinline__ void cdotA(f32x2& acc, f32x2 gv, f32x2 cA) {
    asm("v_pk_fma_f32 %0, %1, %2, %0 op_sel:[0,0,0] op_sel_hi:[0,1,1]"
        : "+v"(acc) : "v"(gv), "v"(cA));
}
static __device__ __forceinline__ void cdotB(f32x2& acc, f32x2 gv, f32x2 cB) {
    asm("v_pk_fma_f32 %0, %1, %2, %0 op_sel:[1,0,0] op_sel_hi:[1,1,1]"
        : "+v"(acc) : "v"(gv), "v"(cB));
}

static __device__ __forceinline__ f32x2 c2(float2 a) {
    f32x2 r; r.x = a.x; r.y = a.y; return r;
}

__global__ void geblnet_setup(const float* __restrict__ w2,
                              float4* __restrict__ CTt) {
    int j = blockIdx.x * blockDim.x + threadIdx.x;
    if (j >= 12 * 169) return;
    int u = j / 169, it = j % 169;
    const float* W = w2 + u * 25 * 25 * 2;
#define WR(v, w) W[((v) * 25 + (w)) * 2]
#define WI(v, w) W[((v) * 25 + (w)) * 2 + 1]
    float c0, c1, c2v, c3;
    if (it < 78) {                       // S pairs, a<=b
        int q = it, a = 0;
        while (q >= 12 - a) { q -= 12 - a; ++a; }
        int b = a + q;
        float ar = WR(a, b) + (a != b ? WR(b, a) : 0.f);
        float ai = WI(a, b) + (a != b ? WI(b, a) : 0.f);
        float br = WR(12 + a, 12 + b) + (a != b ? WR(12 + b, 12 + a) : 0.f);
        float bi = WI(12 + a, 12 + b) + (a != b ? WI(12 + b, 12 + a) : 0.f);
        c0 = ar + br; c1 = bi - ai; c2v = ai + bi; c3 = ar - br;
    } else if (it < 156) {               // Hm pairs, a<=b
        int q = it - 78, a = 0;
        while (q >= 12 - a) { q -= 12 - a; ++a; }
        int b = a + q;
        if (a != b) {
            float gr = WR(a, 12 + b) + WR(12 + b, a);
            float gi = WI(a, 12 + b) + WI(12 + b, a);
            float dr = WR(b, 12 + a) + WR(12 + a, b);
            float di = WI(b, 12 + a) + WI(12 + a, b);
            c0 = gr + dr; c1 = di - gi; c2v = gi + di; c3 = gr - dr;
        } else {
            float er = WR(a, 12 + a) + WR(12 + a, a);
            float ei = WI(a, 12 + a) + WI(12 + a, a);
            c0 = er; c1 = 0.f; c2v = ei; c3 = 0.f;
        }
    } else if (it < 168) {               // trace terms
        int a = it - 156;
        float fr = WR(a, 24) + WR(24, a), fi = WI(a, 24) + WI(24, a);
        float pr = WR(12 + a, 24) + WR(24, 12 + a);
        float pi = WI(12 + a, 24) + WI(24, 12 + a);
        c0 = fr + pr; c1 = pi - fi; c2v = fi + pi; c3 = fr - pr;
    } else {                             // unit-unit
        c0 = 3.f * WR(24, 24); c1 = 0.f; c2v = 3.f * WI(24, 24); c3 = 0.f;
    }
    // Packed layout for P5: pairs (c0,c2) and (c1,c3) adjacent.
    CTt[it * 12 + u] = make_float4(c0, c2v, c1, c3);
#undef WR
#undef WI
}

// Scratch union: bs dead after phase 2b; phase-3..6 scratch reuses it.
union Scr {
    float2 bs[702];                     // B[uu][v][jk], rows exact 9 (5616 B)
    struct {
        float2 tpar[60];                // phase 5 partials
        float2 tr1[12];                 // layer-1 traces (read in phase 4)
        float  sc1[12];                 // combined gerelu+trnorm scale
    } s;
};

__global__ __launch_bounds__(256) void geblnet_main(
    const float2* __restrict__ x2,      // (8192, 10, 9) complex
    const float2* __restrict__ w1g,     // (12,13,13) complex
    const float* __restrict__ dw,       // (24,)
    const float* __restrict__ db,       // (1,)
    const float4* __restrict__ CTt,     // (169,12) packed (c0,c2,c1,c3)
    float* __restrict__ out)            // (8192,)
{
    // Per-wave LDS slices (4 waves, fully independent).
    __shared__ float2 WeGV_[4][170];    //  5440 B
    __shared__ Scr S_[4];               // 22464 B
    __shared__ float2 Hs_[4][108];      //  3456 B
    // total 31360 B -> ~3.3 blocks/CU by the ~102KB pool

    const int wid = threadIdx.x >> 6;
    const int t = threadIdx.x & 63;
    const int p = blockIdx.x * 4 + wid;

    float2* WeGV = WeGV_[wid];
    Scr* Sp = &S_[wid];
    float2* Hs = Hs_[wid];

    // ---- phase 1: ONE coalesced read of x channels 4..9 (54 float2),
    //      write both We layouts (direct ch 0..5, conj-T ch 6..11) + identity.
    if (t < 54) {
        int xc = t / 9, ik = t - xc * 9;
        int i = ik / 3, j = ik - i * 3;
        float2 val = x2[(size_t)p * 90 + 36 + t];       // contiguous 432 B
        WeGV[xc * 10 + ik] = val;                        // direct
        WeGV[(6 + xc) * 10 + j * 3 + i] = make_float2(val.x, -val.y); // conj-T
    } else if (t < 63) {
        int ik = t - 54;
        WeGV[120 + ik] = make_float2((ik % 4 == 0) ? 1.f : 0.f, 0.f); // identity
    }
    wsync();

    // ---- phase 2: layer 1 on all 64 lanes, two u-half passes
    #pragma unroll 1
    for (int g = 0; g < 2; ++g) {
        const int u0 = g * 6;
        // 2a: B[uu][v][jk] = sum_w w1[u0+uu,v,w] * We[w][jk]
        //     8 chains: even/odd-w x A/B half-macros.
        {
            int uu = 0, rem = t;
            #pragma unroll 2
            for (int e = t; e < 702; e += 64) {
                int v = rem / 9, jk = rem - v * 9;
                const float2* cp = w1g + ((u0 + uu) * 13 + v) * 13; // contiguous
                f32x2 a0A = {0.f, 0.f}, a0B = {0.f, 0.f};
                f32x2 a1A = {0.f, 0.f}, a1B = {0.f, 0.f};
                #pragma unroll
                for (int w = 0; w < 12; w += 2) {
                    f32x2 c0 = c2(cp[w]),     e0 = c2(WeGV[w * 10 + jk]);
                    f32x2 c1 = c2(cp[w + 1]), e1 = c2(WeGV[(w + 1) * 10 + jk]);
                    cmacA(a0A, c0, e0);
                    cmacB(a0B, c0, e0);
                    cmacA(a1A, c1, e1);
                    cmacB(a1B, c1, e1);
                }
                {
                    f32x2 c0 = c2(cp[12]), e0 = c2(WeGV[120 + jk]);
                    cmacA(a0A, c0, e0);
                    cmacB(a0B, c0, e0);
                }
                Sp->bs[(uu * 13 + v) * 9 + jk] =
                    make_float2((a0A.x + a0B.x) + (a1A.x + a1B.x),
                                (a0A.y + a0B.y) + (a1A.y + a1B.y));
                rem += 64;
                if (rem >= 117) { rem -= 117; ++uu; }
            }
        }
        wsync();
        // 2b: H[u0+uu][i][k] = sum_{v,j} We[v][i][j] * B[uu][v][j*3+k]
        //     6 chains: 3 j-accs x A/B.
        if (t < 54) {
            int uu = t / 9, ik = t - uu * 9;
            int i = ik / 3, k = ik - i * 3;
            f32x2 h0A = {0.f, 0.f}, h0B = {0.f, 0.f};
            f32x2 h1A = {0.f, 0.f}, h1B = {0.f, 0.f};
            f32x2 h2A = {0.f, 0.f}, h2B = {0.f, 0.f};
            #pragma unroll
            for (int v = 0; v < 13; ++v) {
                const float2* a = &WeGV[v * 10 + i * 3];
                const float2* b = &Sp->bs[(uu * 13 + v) * 9 + k];
                f32x2 a0 = c2(a[0]), b0 = c2(b[0]);
                f32x2 a1 = c2(a[1]), b1 = c2(b[3]);
                f32x2 a2 = c2(a[2]), b2 = c2(b[6]);
                cmacA(h0A, a0, b0); cmacB(h0B, a0, b0);
                cmacA(h1A, a1, b1); cmacB(h1B, a1, b1);
                cmacA(h2A, a2, b2); cmacB(h2B, a2, b2);
            }
            Hs[(u0 + uu) * 9 + ik] =
                make_float2((h0A.x + h0B.x) + (h1A.x + h1B.x) + (h2A.x + h2B.x),
                            (h0A.y + h0B.y) + (h1A.y + h1B.y) + (h2A.y + h2B.y));
        }
        wsync();
    }

    // ---- phase 3: traces + gerelu + trnorm scales (shuffle reduce)
    {
        float2 tt = make_float2(0.f, 0.f);
        float gg = 0.f, tra_v = 0.f;
        if (t < 12) {
            float2 a = Hs[t * 9 + 0], b = Hs[t * 9 + 4], c = Hs[t * 9 + 8];
            tt = make_float2(a.x + b.x + c.x, a.y + b.y + c.y);
            gg = tt.x > 0.f ? tt.x : 0.f;
            tra_v = gg * sqrtf(tt.x * tt.x + tt.y * tt.y);
        }
        float m = tra_v;                 // lanes 12..15 contribute 0
        m += __shfl_xor(m, 1, 16);
        m += __shfl_xor(m, 2, 16);
        m += __shfl_xor(m, 4, 16);
        m += __shfl_xor(m, 8, 16);
        if (t < 12) {
            Sp->s.tr1[t] = tt;
            Sp->s.sc1[t] = gg / fmaxf(m * (1.f / 12.f), THRESH);
        }
    }
    wsync();

    // ---- phase 4: Gram values -> GV (overlays We row-major; dead now)
    for (int it = t; it < 169; it += 64) {
        float2 val;
        if (it < 156) {
            int q = it < 78 ? it : it - 78;
            float fs = sqrtf(625.0f - 8.0f * (float)q);   // exact at bucket edges
            int a = (int)((25.0f - fs) * 0.5f);
            int b = q - (a * (25 - a)) / 2 + a;
            const float2* Ha = &Hs[a * 9];
            const float2* Hb = &Hs[b * 9];
            float s = Sp->s.sc1[a] * Sp->s.sc1[b];
            f32x2 v0A = {0.f, 0.f}, v0B = {0.f, 0.f};
            f32x2 v1A = {0.f, 0.f}, v1B = {0.f, 0.f};
            if (it < 78) {                    // S = tr(Aa Ab)
                #pragma unroll
                for (int i = 0; i < 3; ++i)
                    #pragma unroll
                    for (int jj = 0; jj < 3; ++jj) {
                        f32x2 A = c2(Ha[i * 3 + jj]), B = c2(Hb[jj * 3 + i]);
                        if (((i * 3 + jj) & 1) == 0) {
                            cmacA(v0A, A, B); cmacB(v0B, A, B);
                        } else {
                            cmacA(v1A, A, B); cmacB(v1B, A, B);
                        }
                    }
            } else {                          // Hm = tr(Aa Ab^H)
                #pragma unroll
                for (int e = 0; e < 9; ++e) {
                    f32x2 A = c2(Ha[e]), B = c2(Hb[e]);
                    if ((e & 1) == 0) { cmaccA(v0A, A, B); cmaccB(v0B, A, B); }
                    else              { cmaccA(v1A, A, B); cmaccB(v1B, A, B); }
                }
            }
            val = make_float2(s * ((v0A.x + v0B.x) + (v1A.x + v1B.x)),
                              s * ((v0A.y + v0B.y) + (v1A.y + v1B.y)));
        } else if (it < 168) {
            int a = it - 156;
            float s = Sp->s.sc1[a]; float2 tt = Sp->s.tr1[a];
            val = make_float2(s * tt.x, s * tt.y);
        } else {
            val = make_float2(1.f, 0.f);
        }
        WeGV[it] = val;
    }
    wsync();

    // ---- phase 5: coefficient contraction, lane=(q,u), 60 active
    //      8 chains: 4x unroll x A/B, all NAMED accumulators.
    if (t < 60) {
        int q = t / 12, u = t - q * 12;
        int i0 = q * 34, i1 = (q == 4) ? 169 : i0 + 34;
        f32x2 A0 = {0.f, 0.f}, B0 = {0.f, 0.f};
        f32x2 A1 = {0.f, 0.f}, B1 = {0.f, 0.f};
        f32x2 A2 = {0.f, 0.f}, B2 = {0.f, 0.f};
        f32x2 A3 = {0.f, 0.f}, B3 = {0.f, 0.f};
        int it = i0;
        #pragma unroll 1
        for (; it + 4 <= i1; it += 4) {
            float4 c0v = CTt[(it + 0) * 12 + u];
            float4 c1v = CTt[(it + 1) * 12 + u];
            float4 c2c = CTt[(it + 2) * 12 + u];
            float4 c3v = CTt[(it + 3) * 12 + u];
            f32x2 g0 = c2(WeGV[it + 0]), g1 = c2(WeGV[it + 1]);
            f32x2 g2 = c2(WeGV[it + 2]), g3 = c2(WeGV[it + 3]);
            f32x2 cA, cB;
            cA.x = c0v.x; cA.y = c0v.y; cB.x = c0v.z; cB.y = c0v.w;
            cdotA(A0, g0, cA); cdotB(B0, g0, cB);
            cA.x = c1v.x; cA.y = c1v.y; cB.x = c1v.z; cB.y = c1v.w;
            cdotA(A1, g1, cA); cdotB(B1, g1, cB);
            cA.x = c2c.x; cA.y = c2c.y; cB.x = c2c.z; cB.y = c2c.w;
            cdotA(A2, g2, cA); cdotB(B2, g2, cB);
            cA.x = c3v.x; cA.y = c3v.y; cB.x = c3v.z; cB.y = c3v.w;
            cdotA(A3, g3, cA); cdotB(B3, g3, cB);
        }
        for (; it < i1; ++it) {
            float4 c = CTt[it * 12 + u];
            f32x2 cA, cB;
            cA.x = c.x; cA.y = c.y; cB.x = c.z; cB.y = c.w;
            f32x2 g = c2(WeGV[it]);
            cdotA(A0, g, cA); cdotB(B0, g, cB);
        }
        Sp->s.tpar[u * 5 + q] =
            make_float2(((A0.x + B0.x) + (A1.x + B1.x)) +
                        ((A2.x + B2.x) + (A3.x + B3.x)),
                        ((A0.y + B0.y) + (A1.y + B1.y)) +
                        ((A2.y + B2.y) + (A3.y + B3.y)));
    }
    wsync();

    // ---- phase 6: layer-2 gerelu + trnorm + dense head (shuffle reduce)
    {
        float2 tt = make_float2(0.f, 0.f);
        float gg = 0.f, tra_v = 0.f;
        if (t < 12) {
            #pragma unroll
            for (int q = 0; q < 5; ++q) {
                float2 A = Sp->s.tpar[t * 5 + q];
                tt.x += A.x; tt.y += A.y;
            }
            gg = tt.x > 0.f ? tt.x : 0.f;
            tra_v = gg * sqrtf(tt.x * tt.x + tt.y * tt.y);
        }
        float m = tra_v;                 // lanes 12..15 contribute 0
        m += __shfl_xor(m, 1, 16);
        m += __shfl_xor(m, 2, 16);
        m += __shfl_xor(m, 4, 16);
        m += __shfl_xor(m, 8, 16);
        float term = 0.f;
        if (t < 12) {
            float inv = 1.f / fmaxf(m * (1.f / 12.f), THRESH);
            float s = gg * inv * (1.f / 3.f);
            term = s * (tt.x * dw[2 * t] + tt.y * dw[2 * t + 1]);
        }
        term += __shfl_xor(term, 1, 16);
        term += __shfl_xor(term, 2, 16);
        term += __shfl_xor(term, 4, 16);
        term += __shfl_xor(term, 8, 16);
        if (t == 0) out[p] = term + db[0];
    }
}

extern "C" void kernel_launch(void* const* d_in, const int* in_sizes, int n_in,
                              void* d_out, int out_size, void* d_ws, size_t ws_size,
                              hipStream_t stream) {
    const float* x  = (const float*)d_in[0];
    const float* w1 = (const float*)d_in[1];
    const float* w2 = (const float*)d_in[2];
    const float* dw = (const float*)d_in[3];
    const float* db = (const float*)d_in[4];
    float* outp = (float*)d_out;
    float4* CTt = (float4*)d_ws;          // 12*169*16 B = 32448 B

    geblnet_setup<<<(12 * 169 + 255) / 256, 256, 0, stream>>>(w2, CTt);

    geblnet_main<<<NPTS / 4, 256, 0, stream>>>(
        (const float2*)x, (const float2*)w1, dw, db, CTt, outp);
}